// Round 8
// baseline (1137.578 us; speedup 1.0000x reference)
//
#include <hip/hip_runtime.h>
#include <hip/hip_cooperative_groups.h>
#include <hip/hip_fp16.h>

namespace cg = cooperative_groups;

#define B_    8
#define N_    16384
#define K_    16
#define G_    4
#define CQ_   64
#define CV_   64
#define CQG_  16
#define CVG_  16
#define CLPE_ 16
#define NT_   (B_*G_*N_)   // 524288 threads, one per (b,g,n)

typedef float f4v __attribute__((ext_vector_type(4)));
typedef int   i4v __attribute__((ext_vector_type(4)));

static __device__ __forceinline__ void nt_store4(float* p, float a, float b,
                                                 float c, float d) {
    f4v v = {a, b, c, d};
    __builtin_nontemporal_store(v, (f4v*)p);
}
static __device__ __forceinline__ void nt_store1(float* p, float a) {
    __builtin_nontemporal_store(a, p);
}

union QV { uint4 u; __half2 h[4]; };

// ---------------------------------------------------------------------------
// Shared helpers (used by both the fused cooperative kernel and the split
// fallback kernels). prep_tile: one 256-point tile -> qvT records via LDS
// lane-exchange (full-line coalesced writes), cent zero, xyz4 pack.
// ---------------------------------------------------------------------------
__device__ __forceinline__ void prep_tile(
    const int w, const int t,
    const float* __restrict__ query, const float* __restrict__ value,
    const float* __restrict__ xyz,
    uint4* __restrict__ qvT, float4* __restrict__ xyz4, float* __restrict__ cent,
    unsigned int* __restrict__ sstage)
{
    const int xcd = w & 7;
    const int i   = w >> 3;            // 0..255
    const int bg  = (xcd << 2) | (i >> 6);
    const int n0  = (i & 63) << 8;     // tile's 256 consecutive points
    const int n   = n0 | t;
    const int g   = bg & (G_ - 1);
    const int b   = bg >> 2;
    const int gid = (bg << 14) | n;

    const float* qb = query + (size_t)b*CQ_*N_ + (size_t)g*CQG_*N_ + n;
    const float* vb = value + (size_t)b*CV_*N_ + (size_t)g*CVG_*N_ + n;

    unsigned int u[16];
    #pragma unroll
    for (int q2 = 0; q2 < 8; ++q2) {
        const float a0 = __builtin_nontemporal_load(qb + (size_t)(2*q2+0)*N_);
        const float a1 = __builtin_nontemporal_load(qb + (size_t)(2*q2+1)*N_);
        const __half2 h = __floats2half2_rn(a0, a1);
        u[q2] = *(const unsigned int*)&h;
    }
    #pragma unroll
    for (int q2 = 0; q2 < 8; ++q2) {
        const float a0 = __builtin_nontemporal_load(vb + (size_t)(2*q2+0)*N_);
        const float a1 = __builtin_nontemporal_load(vb + (size_t)(2*q2+1)*N_);
        const __half2 h = __floats2half2_rn(a0, a1);
        u[8+q2] = *(const unsigned int*)&h;
    }

    // stage into stride-17 slot (2 lanes/bank on write side: free)
    #pragma unroll
    for (int k = 0; k < 16; ++k) sstage[t*17 + k] = u[k];

    cent[gid] = 0.f;
    if (g == 0) {
        const size_t pp = (size_t)b*N_ + n;
        xyz4[pp] = make_float4(xyz[pp*3+0], xyz[pp*3+1], xyz[pp*3+2], 0.f);
    }

    __syncthreads();

    // tile's qvT region = 16KB contiguous; wave store instr covers 1KB lines
    uint4* ob = qvT + (size_t)(((size_t)bg << 14) | (unsigned)n0) * 4;
    #pragma unroll
    for (int i2 = 0; i2 < 4; ++i2) {
        const int j = i2*256 + t;          // chunk 0..1023 (16B each)
        const int r = j >> 2, q = j & 3;
        const unsigned int* sp = &sstage[r*17 + q*4];
        ob[j] = make_uint4(sp[0], sp[1], sp[2], sp[3]);
    }
    __syncthreads();   // sstage reusable after this
}

__device__ __forceinline__ void init_AB(
    const int t,
    const float* __restrict__ lpeW, const float* __restrict__ lpeB,
    const float* __restrict__ bnG,  const float* __restrict__ bnB,
    const float* __restrict__ bnM,  const float* __restrict__ bnV,
    float4* __restrict__ sA, float4* __restrict__ sB)
{
    if (t < CLPE_) {
        const float scale = bnG[t] * rsqrtf(bnV[t] + 1e-5f);
        const float shift = (lpeB[t] - bnM[t]) * scale + bnB[t];
        const float w0 = lpeW[t*10+0];
        const float w1 = lpeW[t*10+1], w2 = lpeW[t*10+2], w3 = lpeW[t*10+3];
        const float w4 = lpeW[t*10+4], w5 = lpeW[t*10+5], w6 = lpeW[t*10+6];
        const float w7 = lpeW[t*10+7], w8 = lpeW[t*10+8], w9 = lpeW[t*10+9];
        sA[t] = make_float4(scale*(w1+w4), scale*(w2+w5), scale*(w3+w6), shift);
        sB[t] = make_float4(scale*(w7-w1), scale*(w8-w2), scale*(w9-w3), scale*w0);
    }
}

// main_work: R7 gtl_main body (2 phased slots per block). sbase = 4352 floats.
__device__ __forceinline__ void main_work(
    const int wid, const int t,
    const uint4*  __restrict__ qvT,
    const float4* __restrict__ xyz4,
    const int*    __restrict__ nidx,
    const float4* __restrict__ sA, const float4* __restrict__ sB,
    float* __restrict__ sbase,
    float* __restrict__ out, float* __restrict__ fenc, float* __restrict__ cent)
{
    const int w    = t >> 6;
    const int lane = t & 63;
    const int xcd  = wid & 7;
    const int half = wid >> 3;      // 0..127
    float* swb = sbase + w*(64*17);

    #pragma unroll 1
    for (int p = 0; p < 2; ++p) {
        const int slot = half + (p << 7);          // 0..255
        const int bg   = (xcd << 2) | (slot >> 6);
        const int n    = ((slot & 63) << 8) | t;
        const int b    = bg >> 2;
        const size_t xb = (size_t)b * N_;

        int idx[K_];
        {
            const i4v* ip = (const i4v*)(nidx + ((size_t)b*N_ + n) * K_);
            #pragma unroll
            for (int q4 = 0; q4 < K_/4; ++q4) {
                const i4v v = __builtin_nontemporal_load(ip + q4);
                idx[q4*4+0] = v.x; idx[q4*4+1] = v.y;
                idx[q4*4+2] = v.z; idx[q4*4+3] = v.w;
            }
        }

        const uint4* qvslab = qvT + (size_t)bg * N_ * 4;

        float lq[CQG_];
        {
            QV cA, cB;
            cA.u = qvslab[(size_t)n*4+0];
            cB.u = qvslab[(size_t)n*4+1];
            #pragma unroll
            for (int i2 = 0; i2 < 4; ++i2) {
                const float2 f = __half22float2(cA.h[i2]);
                lq[2*i2+0] = f.x; lq[2*i2+1] = f.y;
            }
            #pragma unroll
            for (int i2 = 0; i2 < 4; ++i2) {
                const float2 f = __half22float2(cB.h[i2]);
                lq[8+2*i2+0] = f.x; lq[8+2*i2+1] = f.y;
            }
        }
        const float4 cpt = xyz4[xb + n];

        float la[K_];
        float accV[CVG_];
        __half2 nbh[2*K_];
        #pragma unroll
        for (int c = 0; c < CVG_; ++c) accV[c] = 0.f;
        float m = -1e30f;

        #pragma unroll 4
        for (int k = 0; k < K_; ++k) {
            const int j = idx[k];
            const uint4* rp = qvslab + (size_t)j*4;   // one 64B line
            QV r0, r1, r2, r3;
            r0.u = rp[0]; r1.u = rp[1]; r2.u = rp[2]; r3.u = rp[3];
            const float4 pp = xyz4[xb + j];

            float s = 0.f;
            #pragma unroll
            for (int i2 = 0; i2 < 4; ++i2) {
                const float2 f = __half22float2(r0.h[i2]);
                s = fmaf(lq[2*i2+0], f.x, s);
                s = fmaf(lq[2*i2+1], f.y, s);
            }
            #pragma unroll
            for (int i2 = 0; i2 < 4; ++i2) {
                const float2 f = __half22float2(r1.h[i2]);
                s = fmaf(lq[8+2*i2+0], f.x, s);
                s = fmaf(lq[8+2*i2+1], f.y, s);
            }
            la[k] = s;

            const float mn = fmaxf(m, s);
            const float sc = __expf(m - mn);
            const float ww = __expf(s - mn);
            m = mn;

            #pragma unroll
            for (int i2 = 0; i2 < 4; ++i2) {
                const float2 f = __half22float2(r2.h[i2]);
                accV[2*i2+0] = fmaf(ww, f.x, accV[2*i2+0]*sc);
                accV[2*i2+1] = fmaf(ww, f.y, accV[2*i2+1]*sc);
            }
            #pragma unroll
            for (int i2 = 0; i2 < 4; ++i2) {
                const float2 f = __half22float2(r3.h[i2]);
                accV[8+2*i2+0] = fmaf(ww, f.x, accV[8+2*i2+0]*sc);
                accV[8+2*i2+1] = fmaf(ww, f.y, accV[8+2*i2+1]*sc);
            }

            const float rx = cpt.x - pp.x, ry = cpt.y - pp.y, rz = cpt.z - pp.z;
            const float d  = sqrtf(fmaf(rx,rx, fmaf(ry,ry, rz*rz)));
            nbh[2*k+0] = __floats2half2_rn(pp.x, pp.y);
            nbh[2*k+1] = __floats2half2_rn(pp.z, d);
        }

        float ssum = 0.f;
        #pragma unroll
        for (int k = 0; k < K_; ++k) {
            const float e = __expf(la[k] - m);
            la[k] = e; ssum += e;
        }
        const float inv = 1.f / ssum;
        #pragma unroll
        for (int k = 0; k < K_; ++k) la[k] *= inv;
        #pragma unroll
        for (int c = 0; c < CVG_; ++c) accV[c] *= inv;

        {
            float* cb = cent + (size_t)bg * N_;
            #pragma unroll
            for (int k = 0; k < K_; ++k) atomicAdd(cb + idx[k], la[k]);
        }

        float basec[CLPE_];
        #pragma unroll
        for (int c = 0; c < CLPE_; ++c) {
            const float4 a = sA[c];
            basec[c] = fmaf(a.x, cpt.x, fmaf(a.y, cpt.y, fmaf(a.z, cpt.z, a.w)));
        }

        float* ob = out + (size_t)bg * (CVG_ + CLPE_) * N_ + n;
        const size_t n0 = (size_t)(n - lane);

        #pragma unroll 2
        for (int c = 0; c < CLPE_; ++c) {
            const float4 wB = sB[c];
            const float base = basec[c];
            float e[K_];
            float acc = 0.f;
            #pragma unroll
            for (int k = 0; k < K_; ++k) {
                const float2 pxy = __half22float2(nbh[2*k+0]);
                const float2 pzd = __half22float2(nbh[2*k+1]);
                float tt = base;
                tt = fmaf(wB.x, pxy.x, tt);
                tt = fmaf(wB.y, pxy.y, tt);
                tt = fmaf(wB.z, pzd.x, tt);
                tt = fmaf(wB.w, pzd.y, tt);
                tt = fmaxf(tt, 0.f);
                e[k] = tt;
                acc  = fmaf(la[k], tt, acc);
            }

            float* sl = swb + lane*17;
            #pragma unroll
            for (int k = 0; k < K_; ++k) sl[k] = e[k];
            __builtin_amdgcn_wave_barrier();

            float* fc = fenc + (((size_t)bg*CLPE_ + c) * N_ + n0) * K_;
            #pragma unroll
            for (int i = 0; i < 4; ++i) {
                const int j  = i*64 + lane;
                const int pt = j >> 2, q = j & 3;
                const float* rp = swb + pt*17 + q*4;
                nt_store4(fc + (size_t)j*4, rp[0], rp[1], rp[2], rp[3]);
            }
            __builtin_amdgcn_wave_barrier();

            nt_store1(ob + (size_t)(CVG_ + c) * N_, acc);
        }

        #pragma unroll
        for (int c = 0; c < CVG_; ++c) nt_store1(ob + (size_t)c * N_, accV[c]);
    }
}

// ---------------------------------------------------------------------------
// Fused cooperative kernel: prep (2 tiles/block, XCD-local) -> grid.sync ->
// main. 1024 blocks x 256 thr, __launch_bounds__(256,4) -> 4 blocks/CU
// co-resident. sstage (17.4KB) reused between phases.
// ---------------------------------------------------------------------------
__global__ __launch_bounds__(256, 4) void gtl_fused(
    const float* __restrict__ query,
    const float* __restrict__ value,
    const float* __restrict__ xyz,
    uint4*  __restrict__ qvT,
    float4* __restrict__ xyz4,
    const int*   __restrict__ nidx,
    const float* __restrict__ lpeW,
    const float* __restrict__ lpeB,
    const float* __restrict__ bnG,
    const float* __restrict__ bnB,
    const float* __restrict__ bnM,
    const float* __restrict__ bnV,
    float* __restrict__ out,
    float* __restrict__ fenc,
    float* __restrict__ cent)
{
    __shared__ float4 sA[CLPE_];
    __shared__ float4 sB[CLPE_];
    __shared__ unsigned int sstage[256*17];   // 17.4KB, both phases

    const int t   = threadIdx.x;
    const int wid = blockIdx.x;               // 0..1023
    const int xcd = wid & 7;
    const int h   = wid >> 3;                 // 0..127

    // phase 1: prep tiles j=2h, 2h+1 of this XCD (orig prep wid = (j<<3)|xcd)
    prep_tile(((h*2+0) << 3) | xcd, t, query, value, xyz, qvT, xyz4, cent,
              sstage);
    prep_tile(((h*2+1) << 3) | xcd, t, query, value, xyz, qvT, xyz4, cent,
              sstage);
    init_AB(t, lpeW, lpeB, bnG, bnB, bnM, bnV, sA, sB);

    cg::this_grid().sync();

    // phase 2: main
    main_work(wid, t, qvT, xyz4, nidx, sA, sB, (float*)sstage,
              out, fenc, cent);
}

// ---------------------------------------------------------------------------
// Split fallback kernels (R7 behavior) if cooperative launch is unavailable.
// ---------------------------------------------------------------------------
__global__ __launch_bounds__(256) void gtl_prep(
    const float* __restrict__ query,
    const float* __restrict__ value,
    const float* __restrict__ xyz,
    uint4*  __restrict__ qvT,
    float4* __restrict__ xyz4,
    float*  __restrict__ cent)
{
    __shared__ unsigned int sstage[256*17];
    prep_tile(blockIdx.x, threadIdx.x, query, value, xyz, qvT, xyz4, cent,
              sstage);
}

__global__ __launch_bounds__(256) void gtl_main(
    const uint4*  __restrict__ qvT,
    const float4* __restrict__ xyz4,
    const int*    __restrict__ nidx,
    const float*  __restrict__ lpeW,
    const float*  __restrict__ lpeB,
    const float*  __restrict__ bnG,
    const float*  __restrict__ bnB,
    const float*  __restrict__ bnM,
    const float*  __restrict__ bnV,
    float* __restrict__ out,
    float* __restrict__ fenc,
    float* __restrict__ cent)
{
    __shared__ float4 sA[CLPE_];
    __shared__ float4 sB[CLPE_];
    __shared__ float  sbuf[4*64*17];
    const int t = threadIdx.x;
    init_AB(t, lpeW, lpeB, bnG, bnB, bnM, bnV, sA, sB);
    __syncthreads();
    main_work(blockIdx.x, t, qvT, xyz4, nidx, sA, sB, sbuf, out, fenc, cent);
}

// ---------------------------------------------------------------------------
// Fallback (verified correct, fp32) if workspace is too small.
// ---------------------------------------------------------------------------
__global__ __launch_bounds__(256) void gtl_fallback(
    const float* __restrict__ xyz,
    const float* __restrict__ query,
    const float* __restrict__ value,
    const int*   __restrict__ nidx,
    const float* __restrict__ lpeW,
    const float* __restrict__ lpeB,
    const float* __restrict__ bnG,
    const float* __restrict__ bnB,
    const float* __restrict__ bnM,
    const float* __restrict__ bnV,
    float* __restrict__ out,
    float* __restrict__ fenc,
    float* __restrict__ cent)
{
    __shared__ float4 sA[CLPE_];
    __shared__ float4 sB[CLPE_];
    const int t = threadIdx.x;
    init_AB(t, lpeW, lpeB, bnG, bnB, bnM, bnV, sA, sB);
    __syncthreads();
    const int gid = blockIdx.x * 256 + t;
    const int n   = gid & (N_ - 1);
    const int bg  = gid >> 14;
    const int g   = bg & (G_ - 1);
    const int b   = bg >> 2;
    const float cx = xyz[(size_t)(b*N_ + n)*3 + 0];
    const float cy = xyz[(size_t)(b*N_ + n)*3 + 1];
    const float cz = xyz[(size_t)(b*N_ + n)*3 + 2];
    int idx[K_];
    const int4* ip = (const int4*)(nidx + (size_t)(b*N_ + n) * K_);
    #pragma unroll
    for (int q4 = 0; q4 < K_/4; ++q4) {
        const int4 v = ip[q4];
        idx[q4*4+0] = v.x; idx[q4*4+1] = v.y; idx[q4*4+2] = v.z; idx[q4*4+3] = v.w;
    }
    const float* qb = query + (size_t)b*CQ_*N_ + (size_t)g*CQG_*N_;
    float lq[CQG_];
    #pragma unroll
    for (int c = 0; c < CQG_; ++c) lq[c] = qb[(size_t)c*N_ + n];
    float la[K_];
    #pragma unroll 4
    for (int k = 0; k < K_; ++k) {
        const float* qj = qb + idx[k];
        float s = 0.f;
        #pragma unroll
        for (int c = 0; c < CQG_; ++c) s = fmaf(lq[c], qj[(size_t)c*N_], s);
        la[k] = s;
    }
    float m = la[0];
    #pragma unroll
    for (int k = 1; k < K_; ++k) m = fmaxf(m, la[k]);
    float ssum = 0.f;
    #pragma unroll
    for (int k = 0; k < K_; ++k) { const float e = __expf(la[k] - m); la[k] = e; ssum += e; }
    const float inv = 1.f / ssum;
    #pragma unroll
    for (int k = 0; k < K_; ++k) la[k] *= inv;
    float* cb = cent + (size_t)bg * N_;
    #pragma unroll
    for (int k = 0; k < K_; ++k) atomicAdd(cb + idx[k], la[k]);
    float basec[CLPE_];
    #pragma unroll
    for (int c = 0; c < CLPE_; ++c) {
        const float4 a = sA[c];
        basec[c] = fmaf(a.x, cx, fmaf(a.y, cy, fmaf(a.z, cz, a.w)));
    }
    const float* vb = value + (size_t)b*CV_*N_ + (size_t)g*CVG_*N_;
    float accV[CVG_], accE[CLPE_];
    #pragma unroll
    for (int c = 0; c < CLPE_; ++c) { accV[c] = 0.f; accE[c] = 0.f; }
    float* fe = fenc + ((size_t)bg * CLPE_ * N_ + n) * K_;
    #pragma unroll 2
    for (int k = 0; k < K_; ++k) {
        const int j = idx[k];
        const float nx = xyz[(size_t)(b*N_ + j)*3 + 0];
        const float ny = xyz[(size_t)(b*N_ + j)*3 + 1];
        const float nz = xyz[(size_t)(b*N_ + j)*3 + 2];
        const float rx = cx - nx, ry = cy - ny, rz = cz - nz;
        const float d  = sqrtf(rx*rx + ry*ry + rz*rz);
        const float w  = la[k];
        const float* vj = vb + j;
        #pragma unroll
        for (int c = 0; c < CLPE_; ++c) {
            const float4 bb = sB[c];
            float e = basec[c];
            e = fmaf(bb.x, nx, e); e = fmaf(bb.y, ny, e);
            e = fmaf(bb.z, nz, e); e = fmaf(bb.w, d,  e);
            e = fmaxf(e, 0.f);
            fe[(size_t)c*(N_*K_) + k] = e;
            accE[c] = fmaf(w, e, accE[c]);
            accV[c] = fmaf(w, vj[(size_t)c*N_], accV[c]);
        }
    }
    float* ob = out + (size_t)bg * (CVG_ + CLPE_) * N_ + n;
    #pragma unroll
    for (int c = 0; c < CVG_; ++c)  ob[(size_t)c*N_]        = accV[c];
    #pragma unroll
    for (int c = 0; c < CLPE_; ++c) ob[(size_t)(CVG_+c)*N_] = accE[c];
}

extern "C" void kernel_launch(void* const* d_in, const int* in_sizes, int n_in,
                              void* d_out, int out_size, void* d_ws, size_t ws_size,
                              hipStream_t stream) {
    (void)in_sizes; (void)n_in; (void)out_size;

    const float* xyz   = (const float*)d_in[0];
    const float* query = (const float*)d_in[1];
    const float* value = (const float*)d_in[2];
    const int*   nidx  = (const int*)  d_in[3];
    const float* lpeW  = (const float*)d_in[5];
    const float* lpeB  = (const float*)d_in[6];
    const float* bnG   = (const float*)d_in[7];
    const float* bnB   = (const float*)d_in[8];
    const float* bnM   = (const float*)d_in[9];
    const float* bnV   = (const float*)d_in[10];

    float* out  = (float*)d_out;                                  // B*128*N
    float* fenc = out  + (size_t)B_ * (G_*(CVG_+CLPE_)) * N_;     // B*G*16*N*K
    float* cent = fenc + (size_t)B_ * G_ * CLPE_ * N_ * K_;       // B*G*N

    const size_t qv_bytes   = (size_t)NT_ * 64;                   // 33.5 MB
    const size_t xyz4_bytes = (size_t)B_ * N_ * sizeof(float4);   // 2 MB
    const size_t need = qv_bytes + xyz4_bytes;

    if (ws_size >= need) {
        uint4*  qvT  = (uint4*)d_ws;
        float4* xyz4 = (float4*)((char*)d_ws + qv_bytes);

        // try single-dispatch cooperative fused kernel
        const float *a_q = query, *a_v = value, *a_x = xyz;
        uint4*  a_qv = qvT;
        float4* a_x4 = xyz4;
        const int* a_ni = nidx;
        const float *a_lw = lpeW, *a_lb = lpeB;
        const float *a_g = bnG, *a_b = bnB, *a_m = bnM, *a_vv = bnV;
        float *a_o = out, *a_f = fenc, *a_c = cent;
        void* args[15] = {&a_q, &a_v, &a_x, &a_qv, &a_x4, &a_ni,
                          &a_lw, &a_lb, &a_g, &a_b, &a_m, &a_vv,
                          &a_o, &a_f, &a_c};
        hipError_t e = hipLaunchCooperativeKernel(
            reinterpret_cast<void*>(gtl_fused), dim3(NT_/512), dim3(256),
            args, 0u, stream);
        if (e != hipSuccess) {
            // split fallback (R7 path)
            hipLaunchKernelGGL(gtl_prep, dim3(NT_/256), dim3(256), 0, stream,
                               query, value, xyz, qvT, xyz4, cent);
            hipLaunchKernelGGL(gtl_main, dim3(NT_/512), dim3(256), 0, stream,
                               qvT, xyz4, nidx, lpeW, lpeB, bnG, bnB, bnM, bnV,
                               out, fenc, cent);
        }
    } else {
        (void)hipMemsetAsync(cent, 0, sizeof(float) * (size_t)B_ * G_ * N_, stream);
        hipLaunchKernelGGL(gtl_fallback, dim3(NT_/256), dim3(256), 0, stream,
                           xyz, query, value, nidx, lpeW, lpeB, bnG, bnB, bnM, bnV,
                           out, fenc, cent);
    }
}

// Round 9
// 1017.863 us; speedup vs baseline: 1.1176x; 1.1176x over previous
//
#include <hip/hip_runtime.h>
#include <hip/hip_fp16.h>

#define B_    8
#define N_    16384
#define K_    16
#define G_    4
#define CQ_   64
#define CV_   64
#define CQG_  16
#define CVG_  16
#define CLPE_ 16
#define NT_   (B_*G_*N_)   // 524288 threads, one per (b,g,n)

typedef float f4v __attribute__((ext_vector_type(4)));
typedef int   i4v __attribute__((ext_vector_type(4)));

union QV { uint4 u; __half2 h[4]; };

// ---------------------------------------------------------------------------
// prep_tile: one 256-point tile -> qvT records via LDS lane-exchange
// (full-line coalesced writes), cent zero, xyz4 pack. XCD-aligned mapping.
// ---------------------------------------------------------------------------
__device__ __forceinline__ void prep_tile(
    const int w, const int t,
    const float* __restrict__ query, const float* __restrict__ value,
    const float* __restrict__ xyz,
    uint4* __restrict__ qvT, float4* __restrict__ xyz4, float* __restrict__ cent,
    unsigned int* __restrict__ sstage)
{
    const int xcd = w & 7;
    const int i   = w >> 3;            // 0..255
    const int bg  = (xcd << 2) | (i >> 6);
    const int n0  = (i & 63) << 8;     // tile's 256 consecutive points
    const int n   = n0 | t;
    const int g   = bg & (G_ - 1);
    const int b   = bg >> 2;
    const int gid = (bg << 14) | n;

    const float* qb = query + (size_t)b*CQ_*N_ + (size_t)g*CQG_*N_ + n;
    const float* vb = value + (size_t)b*CV_*N_ + (size_t)g*CVG_*N_ + n;

    unsigned int u[16];
    #pragma unroll
    for (int q2 = 0; q2 < 8; ++q2) {
        const float a0 = __builtin_nontemporal_load(qb + (size_t)(2*q2+0)*N_);
        const float a1 = __builtin_nontemporal_load(qb + (size_t)(2*q2+1)*N_);
        const __half2 h = __floats2half2_rn(a0, a1);
        u[q2] = *(const unsigned int*)&h;
    }
    #pragma unroll
    for (int q2 = 0; q2 < 8; ++q2) {
        const float a0 = __builtin_nontemporal_load(vb + (size_t)(2*q2+0)*N_);
        const float a1 = __builtin_nontemporal_load(vb + (size_t)(2*q2+1)*N_);
        const __half2 h = __floats2half2_rn(a0, a1);
        u[8+q2] = *(const unsigned int*)&h;
    }

    #pragma unroll
    for (int k = 0; k < 16; ++k) sstage[t*17 + k] = u[k];

    cent[gid] = 0.f;
    if (g == 0) {
        const size_t pp = (size_t)b*N_ + n;
        xyz4[pp] = make_float4(xyz[pp*3+0], xyz[pp*3+1], xyz[pp*3+2], 0.f);
    }

    __syncthreads();

    uint4* ob = qvT + (size_t)(((size_t)bg << 14) | (unsigned)n0) * 4;
    #pragma unroll
    for (int i2 = 0; i2 < 4; ++i2) {
        const int j = i2*256 + t;          // chunk 0..1023 (16B each)
        const int r = j >> 2, q = j & 3;
        const unsigned int* sp = &sstage[r*17 + q*4];
        ob[j] = make_uint4(sp[0], sp[1], sp[2], sp[3]);
    }
}

__device__ __forceinline__ void init_AB(
    const int t,
    const float* __restrict__ lpeW, const float* __restrict__ lpeB,
    const float* __restrict__ bnG,  const float* __restrict__ bnB,
    const float* __restrict__ bnM,  const float* __restrict__ bnV,
    float4* __restrict__ sA, float4* __restrict__ sB)
{
    if (t < CLPE_) {
        const float scale = bnG[t] * rsqrtf(bnV[t] + 1e-5f);
        const float shift = (lpeB[t] - bnM[t]) * scale + bnB[t];
        const float w0 = lpeW[t*10+0];
        const float w1 = lpeW[t*10+1], w2 = lpeW[t*10+2], w3 = lpeW[t*10+3];
        const float w4 = lpeW[t*10+4], w5 = lpeW[t*10+5], w6 = lpeW[t*10+6];
        const float w7 = lpeW[t*10+7], w8 = lpeW[t*10+8], w9 = lpeW[t*10+9];
        sA[t] = make_float4(scale*(w1+w4), scale*(w2+w5), scale*(w3+w6), shift);
        sB[t] = make_float4(scale*(w7-w1), scale*(w8-w2), scale*(w9-w3), scale*w0);
    }
}

// ---------------------------------------------------------------------------
// Kernel 1: transpose + fp16-pack (R7 structure).
// ---------------------------------------------------------------------------
__global__ __launch_bounds__(256) void gtl_prep(
    const float* __restrict__ query,
    const float* __restrict__ value,
    const float* __restrict__ xyz,
    uint4*  __restrict__ qvT,
    float4* __restrict__ xyz4,
    float*  __restrict__ cent)
{
    __shared__ unsigned int sstage[256*17];
    prep_tile(blockIdx.x, threadIdx.x, query, value, xyz, qvT, xyz4, cent,
              sstage);
}

// ---------------------------------------------------------------------------
// Kernel 2: fused main pass, online softmax (R7 structure). SINGLE CHANGE
// this round: fenc/out stores are PLAIN CACHED stores, not non-temporal.
// Lines are already full (LDS lane-exchange), so L2 assembles/writes back at
// the cached-path BW; tests whether the NT write path was capping ~2.2 TB/s.
// ---------------------------------------------------------------------------
__global__ __launch_bounds__(256) void gtl_main(
    const uint4*  __restrict__ qvT,
    const float4* __restrict__ xyz4,
    const int*    __restrict__ nidx,
    const float*  __restrict__ lpeW,
    const float*  __restrict__ lpeB,
    const float*  __restrict__ bnG,
    const float*  __restrict__ bnB,
    const float*  __restrict__ bnM,
    const float*  __restrict__ bnV,
    float* __restrict__ out,
    float* __restrict__ fenc,
    float* __restrict__ cent)
{
    __shared__ float4 sA[CLPE_];
    __shared__ float4 sB[CLPE_];
    __shared__ float  sbuf[4][64*17];     // per-wave fenc staging (17.4KB)

    const int t    = threadIdx.x;
    const int w    = t >> 6;
    const int lane = t & 63;

    init_AB(t, lpeW, lpeB, bnG, bnB, bnM, bnV, sA, sB);
    __syncthreads();

    const int wid  = blockIdx.x;    // 0..1023
    const int xcd  = wid & 7;
    const int half = wid >> 3;      // 0..127

    #pragma unroll 1
    for (int p = 0; p < 2; ++p) {
        const int slot = half + (p << 7);          // 0..255
        const int bg   = (xcd << 2) | (slot >> 6);
        const int n    = ((slot & 63) << 8) | t;
        const int b    = bg >> 2;
        const size_t xb = (size_t)b * N_;

        int idx[K_];
        {
            const i4v* ip = (const i4v*)(nidx + ((size_t)b*N_ + n) * K_);
            #pragma unroll
            for (int q4 = 0; q4 < K_/4; ++q4) {
                const i4v v = __builtin_nontemporal_load(ip + q4);
                idx[q4*4+0] = v.x; idx[q4*4+1] = v.y;
                idx[q4*4+2] = v.z; idx[q4*4+3] = v.w;
            }
        }

        const uint4* qvslab = qvT + (size_t)bg * N_ * 4;

        float lq[CQG_];
        {
            QV cA, cB;
            cA.u = qvslab[(size_t)n*4+0];
            cB.u = qvslab[(size_t)n*4+1];
            #pragma unroll
            for (int i2 = 0; i2 < 4; ++i2) {
                const float2 f = __half22float2(cA.h[i2]);
                lq[2*i2+0] = f.x; lq[2*i2+1] = f.y;
            }
            #pragma unroll
            for (int i2 = 0; i2 < 4; ++i2) {
                const float2 f = __half22float2(cB.h[i2]);
                lq[8+2*i2+0] = f.x; lq[8+2*i2+1] = f.y;
            }
        }
        const float4 cpt = xyz4[xb + n];

        float la[K_];
        float accV[CVG_];
        __half2 nbh[2*K_];
        #pragma unroll
        for (int c = 0; c < CVG_; ++c) accV[c] = 0.f;
        float m = -1e30f;

        #pragma unroll 4
        for (int k = 0; k < K_; ++k) {
            const int j = idx[k];
            const uint4* rp = qvslab + (size_t)j*4;   // one 64B line
            QV r0, r1, r2, r3;
            r0.u = rp[0]; r1.u = rp[1]; r2.u = rp[2]; r3.u = rp[3];
            const float4 pp = xyz4[xb + j];

            float s = 0.f;
            #pragma unroll
            for (int i2 = 0; i2 < 4; ++i2) {
                const float2 f = __half22float2(r0.h[i2]);
                s = fmaf(lq[2*i2+0], f.x, s);
                s = fmaf(lq[2*i2+1], f.y, s);
            }
            #pragma unroll
            for (int i2 = 0; i2 < 4; ++i2) {
                const float2 f = __half22float2(r1.h[i2]);
                s = fmaf(lq[8+2*i2+0], f.x, s);
                s = fmaf(lq[8+2*i2+1], f.y, s);
            }
            la[k] = s;

            const float mn = fmaxf(m, s);
            const float sc = __expf(m - mn);
            const float ww = __expf(s - mn);
            m = mn;

            #pragma unroll
            for (int i2 = 0; i2 < 4; ++i2) {
                const float2 f = __half22float2(r2.h[i2]);
                accV[2*i2+0] = fmaf(ww, f.x, accV[2*i2+0]*sc);
                accV[2*i2+1] = fmaf(ww, f.y, accV[2*i2+1]*sc);
            }
            #pragma unroll
            for (int i2 = 0; i2 < 4; ++i2) {
                const float2 f = __half22float2(r3.h[i2]);
                accV[8+2*i2+0] = fmaf(ww, f.x, accV[8+2*i2+0]*sc);
                accV[8+2*i2+1] = fmaf(ww, f.y, accV[8+2*i2+1]*sc);
            }

            const float rx = cpt.x - pp.x, ry = cpt.y - pp.y, rz = cpt.z - pp.z;
            const float d  = sqrtf(fmaf(rx,rx, fmaf(ry,ry, rz*rz)));
            nbh[2*k+0] = __floats2half2_rn(pp.x, pp.y);
            nbh[2*k+1] = __floats2half2_rn(pp.z, d);
        }

        float ssum = 0.f;
        #pragma unroll
        for (int k = 0; k < K_; ++k) {
            const float e = __expf(la[k] - m);
            la[k] = e; ssum += e;
        }
        const float inv = 1.f / ssum;
        #pragma unroll
        for (int k = 0; k < K_; ++k) la[k] *= inv;
        #pragma unroll
        for (int c = 0; c < CVG_; ++c) accV[c] *= inv;

        {
            float* cb = cent + (size_t)bg * N_;
            #pragma unroll
            for (int k = 0; k < K_; ++k) atomicAdd(cb + idx[k], la[k]);
        }

        float basec[CLPE_];
        #pragma unroll
        for (int c = 0; c < CLPE_; ++c) {
            const float4 a = sA[c];
            basec[c] = fmaf(a.x, cpt.x, fmaf(a.y, cpt.y, fmaf(a.z, cpt.z, a.w)));
        }

        float* ob = out + (size_t)bg * (CVG_ + CLPE_) * N_ + n;
        const size_t n0 = (size_t)(n - lane);
        float* swb = &sbuf[w][0];

        #pragma unroll 2
        for (int c = 0; c < CLPE_; ++c) {
            const float4 wB = sB[c];
            const float base = basec[c];
            float e[K_];
            float acc = 0.f;
            #pragma unroll
            for (int k = 0; k < K_; ++k) {
                const float2 pxy = __half22float2(nbh[2*k+0]);
                const float2 pzd = __half22float2(nbh[2*k+1]);
                float tt = base;
                tt = fmaf(wB.x, pxy.x, tt);
                tt = fmaf(wB.y, pxy.y, tt);
                tt = fmaf(wB.z, pzd.x, tt);
                tt = fmaf(wB.w, pzd.y, tt);
                tt = fmaxf(tt, 0.f);
                e[k] = tt;
                acc  = fmaf(la[k], tt, acc);
            }

            float* sl = swb + lane*17;
            #pragma unroll
            for (int k = 0; k < K_; ++k) sl[k] = e[k];
            __builtin_amdgcn_wave_barrier();

            // wave-coalesced full-line PLAIN stores: instr i covers 1KB
            float4* fc = (float4*)(fenc + (((size_t)bg*CLPE_ + c) * N_ + n0) * K_);
            #pragma unroll
            for (int i = 0; i < 4; ++i) {
                const int j  = i*64 + lane;        // chunk 0..255 (16B each)
                const int pt = j >> 2, q = j & 3;
                const float* rp = swb + pt*17 + q*4;
                fc[j] = make_float4(rp[0], rp[1], rp[2], rp[3]);
            }
            __builtin_amdgcn_wave_barrier();

            ob[(size_t)(CVG_ + c) * N_] = acc;
        }

        #pragma unroll
        for (int c = 0; c < CVG_; ++c) ob[(size_t)c * N_] = accV[c];
    }
}

// ---------------------------------------------------------------------------
// Fallback (verified correct, fp32) if workspace is too small.
// ---------------------------------------------------------------------------
__global__ __launch_bounds__(256) void gtl_fallback(
    const float* __restrict__ xyz,
    const float* __restrict__ query,
    const float* __restrict__ value,
    const int*   __restrict__ nidx,
    const float* __restrict__ lpeW,
    const float* __restrict__ lpeB,
    const float* __restrict__ bnG,
    const float* __restrict__ bnB,
    const float* __restrict__ bnM,
    const float* __restrict__ bnV,
    float* __restrict__ out,
    float* __restrict__ fenc,
    float* __restrict__ cent)
{
    __shared__ float4 sA[CLPE_];
    __shared__ float4 sB[CLPE_];
    const int t = threadIdx.x;
    init_AB(t, lpeW, lpeB, bnG, bnB, bnM, bnV, sA, sB);
    __syncthreads();
    const int gid = blockIdx.x * 256 + t;
    const int n   = gid & (N_ - 1);
    const int bg  = gid >> 14;
    const int g   = bg & (G_ - 1);
    const int b   = bg >> 2;
    const float cx = xyz[(size_t)(b*N_ + n)*3 + 0];
    const float cy = xyz[(size_t)(b*N_ + n)*3 + 1];
    const float cz = xyz[(size_t)(b*N_ + n)*3 + 2];
    int idx[K_];
    const int4* ip = (const int4*)(nidx + (size_t)(b*N_ + n) * K_);
    #pragma unroll
    for (int q4 = 0; q4 < K_/4; ++q4) {
        const int4 v = ip[q4];
        idx[q4*4+0] = v.x; idx[q4*4+1] = v.y; idx[q4*4+2] = v.z; idx[q4*4+3] = v.w;
    }
    const float* qb = query + (size_t)b*CQ_*N_ + (size_t)g*CQG_*N_;
    float lq[CQG_];
    #pragma unroll
    for (int c = 0; c < CQG_; ++c) lq[c] = qb[(size_t)c*N_ + n];
    float la[K_];
    #pragma unroll 4
    for (int k = 0; k < K_; ++k) {
        const float* qj = qb + idx[k];
        float s = 0.f;
        #pragma unroll
        for (int c = 0; c < CQG_; ++c) s = fmaf(lq[c], qj[(size_t)c*N_], s);
        la[k] = s;
    }
    float m = la[0];
    #pragma unroll
    for (int k = 1; k < K_; ++k) m = fmaxf(m, la[k]);
    float ssum = 0.f;
    #pragma unroll
    for (int k = 0; k < K_; ++k) { const float e = __expf(la[k] - m); la[k] = e; ssum += e; }
    const float inv = 1.f / ssum;
    #pragma unroll
    for (int k = 0; k < K_; ++k) la[k] *= inv;
    float* cb = cent + (size_t)bg * N_;
    #pragma unroll
    for (int k = 0; k < K_; ++k) atomicAdd(cb + idx[k], la[k]);
    float basec[CLPE_];
    #pragma unroll
    for (int c = 0; c < CLPE_; ++c) {
        const float4 a = sA[c];
        basec[c] = fmaf(a.x, cx, fmaf(a.y, cy, fmaf(a.z, cz, a.w)));
    }
    const float* vb = value + (size_t)b*CV_*N_ + (size_t)g*CVG_*N_;
    float accV[CVG_], accE[CLPE_];
    #pragma unroll
    for (int c = 0; c < CLPE_; ++c) { accV[c] = 0.f; accE[c] = 0.f; }
    float* fe = fenc + ((size_t)bg * CLPE_ * N_ + n) * K_;
    #pragma unroll 2
    for (int k = 0; k < K_; ++k) {
        const int j = idx[k];
        const float nx = xyz[(size_t)(b*N_ + j)*3 + 0];
        const float ny = xyz[(size_t)(b*N_ + j)*3 + 1];
        const float nz = xyz[(size_t)(b*N_ + j)*3 + 2];
        const float rx = cx - nx, ry = cy - ny, rz = cz - nz;
        const float d  = sqrtf(rx*rx + ry*ry + rz*rz);
        const float w  = la[k];
        const float* vj = vb + j;
        #pragma unroll
        for (int c = 0; c < CLPE_; ++c) {
            const float4 bb = sB[c];
            float e = basec[c];
            e = fmaf(bb.x, nx, e); e = fmaf(bb.y, ny, e);
            e = fmaf(bb.z, nz, e); e = fmaf(bb.w, d,  e);
            e = fmaxf(e, 0.f);
            fe[(size_t)c*(N_*K_) + k] = e;
            accE[c] = fmaf(w, e, accE[c]);
            accV[c] = fmaf(w, vj[(size_t)c*N_], accV[c]);
        }
    }
    float* ob = out + (size_t)bg * (CVG_ + CLPE_) * N_ + n;
    #pragma unroll
    for (int c = 0; c < CVG_; ++c)  ob[(size_t)c*N_]        = accV[c];
    #pragma unroll
    for (int c = 0; c < CLPE_; ++c) ob[(size_t)(CVG_+c)*N_] = accE[c];
}

extern "C" void kernel_launch(void* const* d_in, const int* in_sizes, int n_in,
                              void* d_out, int out_size, void* d_ws, size_t ws_size,
                              hipStream_t stream) {
    (void)in_sizes; (void)n_in; (void)out_size;

    const float* xyz   = (const float*)d_in[0];
    const float* query = (const float*)d_in[1];
    const float* value = (const float*)d_in[2];
    const int*   nidx  = (const int*)  d_in[3];
    const float* lpeW  = (const float*)d_in[5];
    const float* lpeB  = (const float*)d_in[6];
    const float* bnG   = (const float*)d_in[7];
    const float* bnB   = (const float*)d_in[8];
    const float* bnM   = (const float*)d_in[9];
    const float* bnV   = (const float*)d_in[10];

    float* out  = (float*)d_out;                                  // B*128*N
    float* fenc = out  + (size_t)B_ * (G_*(CVG_+CLPE_)) * N_;     // B*G*16*N*K
    float* cent = fenc + (size_t)B_ * G_ * CLPE_ * N_ * K_;       // B*G*N

    const size_t qv_bytes   = (size_t)NT_ * 64;                   // 33.5 MB
    const size_t xyz4_bytes = (size_t)B_ * N_ * sizeof(float4);   // 2 MB
    const size_t need = qv_bytes + xyz4_bytes;

    if (ws_size >= need) {
        uint4*  qvT  = (uint4*)d_ws;
        float4* xyz4 = (float4*)((char*)d_ws + qv_bytes);
        hipLaunchKernelGGL(gtl_prep, dim3(NT_/256), dim3(256), 0, stream,
                           query, value, xyz, qvT, xyz4, cent);
        hipLaunchKernelGGL(gtl_main, dim3(NT_/512), dim3(256), 0, stream,
                           qvT, xyz4, nidx, lpeW, lpeB, bnG, bnB, bnM, bnV,
                           out, fenc, cent);
    } else {
        (void)hipMemsetAsync(cent, 0, sizeof(float) * (size_t)B_ * G_ * N_, stream);
        hipLaunchKernelGGL(gtl_fallback, dim3(NT_/256), dim3(256), 0, stream,
                           xyz, query, value, nidx, lpeW, lpeB, bnG, bnB, bnM, bnV,
                           out, fenc, cent);
    }
}